// Round 6
// baseline (204.263 us; speedup 1.0000x reference)
//
#include <hip/hip_runtime.h>

#define BATCH    2048
#define FLAT_IN  512
#define PROJ_DIM 256
#define HEADS    16384
#define ACT_DIM  64

typedef __attribute__((ext_vector_type(8))) short short8;   // 8 bf16/f16 bits
typedef _Float16 half8 __attribute__((ext_vector_type(8))); // 8 f16 (4 VGPR)
typedef __attribute__((ext_vector_type(4))) float floatx4;  // MFMA C/D

__device__ __forceinline__ unsigned short f2bf(float x) {
  unsigned u = __float_as_uint(x);
  u += 0x7fff + ((u >> 16) & 1);
  return (unsigned short)(u >> 16);
}
__device__ __forceinline__ float bf2f(unsigned short b) {
  return __uint_as_float(((unsigned)b) << 16);
}
__device__ __forceinline__ unsigned short f2h(float x) {
  _Float16 h = (_Float16)x;   // RNE
  return __builtin_bit_cast(unsigned short, h);
}

__device__ __forceinline__ void top2_ins(float v, int h, float& b1, int& i1,
                                         float& b2, int& i2) {
  if (v > b1 || (v == b1 && h < i1)) { b2 = b1; i2 = i1; b1 = v; i1 = h; }
  else if (v > b2 || (v == b2 && h < i2)) { b2 = v; i2 = h; }
}

// ---------------------------------------------------------------------------
// prep: [0,2048) mem fp32 -> f16 ; [2048,2080) transpose+split rp -> bf16
// ---------------------------------------------------------------------------
__global__ __launch_bounds__(256) void prep(
    const float* __restrict__ rp, const float* __restrict__ mem,
    unsigned short* __restrict__ rpT_hi, unsigned short* __restrict__ rpT_mid,
    unsigned short* __restrict__ mem_f16)
{
  const int tid = threadIdx.x;
  const int b = blockIdx.x;
  if (b < 2048) {
    int i2 = b * 256 + tid;                   // 8-float granule
    float4 x = ((const float4*)mem)[2 * i2];
    float4 y = ((const float4*)mem)[2 * i2 + 1];
    short8 o;
    o[0] = (short)f2h(x.x); o[1] = (short)f2h(x.y);
    o[2] = (short)f2h(x.z); o[3] = (short)f2h(x.w);
    o[4] = (short)f2h(y.x); o[5] = (short)f2h(y.y);
    o[6] = (short)f2h(y.z); o[7] = (short)f2h(y.w);
    ((short8*)mem_f16)[i2] = o;
  } else {
    __shared__ float t[64][65];
    int bid = b - 2048;
    int k0 = (bid >> 2) * 64, n0 = (bid & 3) * 64;
#pragma unroll
    for (int it = 0; it < 16; ++it) {
      int lin = it * 256 + tid;
      int kr = lin >> 6, nc = lin & 63;
      t[kr][nc] = rp[(size_t)(k0 + kr) * PROJ_DIM + n0 + nc];
    }
    __syncthreads();
#pragma unroll
    for (int it = 0; it < 16; ++it) {
      int lin = it * 256 + tid;
      int nr = lin >> 6, kc = lin & 63;
      float v = t[kc][nr];
      unsigned short hh = f2bf(v);
      rpT_hi [(size_t)(n0 + nr) * FLAT_IN + k0 + kc] = hh;
      rpT_mid[(size_t)(n0 + nr) * FLAT_IN + k0 + kc] = f2bf(v - bf2f(hh));
    }
  }
}

// ---------------------------------------------------------------------------
// gemm_proj: s = state @ rp, 3-term split-bf16 MFMA, register-prefetch
// pipeline. Reads raw fp32 state (hi/mid split done during ds_write).
// Tile 64x64, BK=64, grid (32,4), 256 thr, wave tile 32x32.
// Epilogue writes s (fp32) + s_f16.
// ---------------------------------------------------------------------------
__global__ __launch_bounds__(256, 3) void gemm_proj(
    const float* __restrict__ state,
    const unsigned short* __restrict__ Bhi, const unsigned short* __restrict__ Bmid,
    float* __restrict__ S, unsigned short* __restrict__ Sf16)
{
  __shared__ __align__(16) unsigned short smAhi [64 * 64];
  __shared__ __align__(16) unsigned short smAmid[64 * 64];
  __shared__ __align__(16) unsigned short smBhi [64 * 64];
  __shared__ __align__(16) unsigned short smBmid[64 * 64];
  const int tid = threadIdx.x;
  const int lane = tid & 63, w = tid >> 6;
  const int quad = lane >> 4, col = lane & 15;
  const int wm = (w >> 1) * 32, wn = (w & 1) * 32;
  const int m0 = blockIdx.x * 64, n0 = blockIdx.y * 64;

  floatx4 acc[2][2];
#pragma unroll
  for (int i = 0; i < 2; ++i)
#pragma unroll
    for (int j = 0; j < 2; ++j) {
      acc[i][j][0] = 0.f; acc[i][j][1] = 0.f;
      acc[i][j][2] = 0.f; acc[i][j][3] = 0.f;
    }

  // granule geometry: per plane 512 granules (64 rows x 8 slots of 8 elems)
  const int P0 = tid, P1 = tid + 256;
  const int r0 = P0 >> 3, kl0 = (P0 & 7) ^ (r0 & 7);
  const int r1 = P1 >> 3, kl1 = (P1 & 7) ^ (r1 & 7);

  float4 pa[2][2];     // fp32 state: 2 granules x 2 float4 (8 floats)
  float4 pbh[2], pbm[2];

  auto gload = [&](int kc) {
    const float* a0 = state + (size_t)(m0 + r0) * FLAT_IN + kc + kl0 * 8;
    const float* a1 = state + (size_t)(m0 + r1) * FLAT_IN + kc + kl1 * 8;
    pa[0][0] = *(const float4*)a0; pa[0][1] = *(const float4*)(a0 + 4);
    pa[1][0] = *(const float4*)a1; pa[1][1] = *(const float4*)(a1 + 4);
    pbh[0] = *(const float4*)(Bhi  + (size_t)(n0 + r0) * FLAT_IN + kc + kl0 * 8);
    pbh[1] = *(const float4*)(Bhi  + (size_t)(n0 + r1) * FLAT_IN + kc + kl1 * 8);
    pbm[0] = *(const float4*)(Bmid + (size_t)(n0 + r0) * FLAT_IN + kc + kl0 * 8);
    pbm[1] = *(const float4*)(Bmid + (size_t)(n0 + r1) * FLAT_IN + kc + kl1 * 8);
  };
  auto swrite = [&]() {
#pragma unroll
    for (int t = 0; t < 2; ++t) {
      int P = t ? P1 : P0;
      float f[8] = {pa[t][0].x, pa[t][0].y, pa[t][0].z, pa[t][0].w,
                    pa[t][1].x, pa[t][1].y, pa[t][1].z, pa[t][1].w};
      short8 vh, vm;
#pragma unroll
      for (int q = 0; q < 8; ++q) {
        unsigned short hh = f2bf(f[q]);
        vh[q] = (short)hh;
        vm[q] = (short)f2bf(f[q] - bf2f(hh));
      }
      *(short8*)&smAhi [P * 8] = vh;
      *(short8*)&smAmid[P * 8] = vm;
      *(float4*)&smBhi [P * 8] = pbh[t];
      *(float4*)&smBmid[P * 8] = pbm[t];
    }
  };

  gload(0);
  swrite();
  __syncthreads();

  for (int it = 0; it < 8; ++it) {
    if (it < 7) gload((it + 1) * 64);
#pragma unroll
    for (int ks = 0; ks < 2; ++ks) {
      short8 bf[2][2];
#pragma unroll
      for (int j = 0; j < 2; ++j) {
        int rr = wn + j * 16 + col;
        int off = rr * 64 + (((ks * 4 + quad) ^ (rr & 7)) * 8);
        bf[j][0] = *(const short8*)&smBhi [off];
        bf[j][1] = *(const short8*)&smBmid[off];
      }
#pragma unroll
      for (int i = 0; i < 2; ++i) {
        int rr = wm + i * 16 + col;
        int off = rr * 64 + (((ks * 4 + quad) ^ (rr & 7)) * 8);
        short8 a0 = *(const short8*)&smAhi [off];
        short8 a1 = *(const short8*)&smAmid[off];
#pragma unroll
        for (int j = 0; j < 2; ++j) {
          acc[i][j] = __builtin_amdgcn_mfma_f32_16x16x32_bf16(a0, bf[j][0], acc[i][j], 0, 0, 0);
          acc[i][j] = __builtin_amdgcn_mfma_f32_16x16x32_bf16(a0, bf[j][1], acc[i][j], 0, 0, 0);
          acc[i][j] = __builtin_amdgcn_mfma_f32_16x16x32_bf16(a1, bf[j][0], acc[i][j], 0, 0, 0);
        }
      }
    }
    __syncthreads();
    if (it < 7) { swrite(); __syncthreads(); }
  }

#pragma unroll
  for (int i = 0; i < 2; ++i)
#pragma unroll
    for (int j = 0; j < 2; ++j)
#pragma unroll
      for (int r = 0; r < 4; ++r) {
        int row = m0 + wm + i * 16 + quad * 4 + r;
        int c   = n0 + wn + j * 16 + col;
        float v = acc[i][j][r];
        S   [(size_t)row * PROJ_DIM + c] = v;
        Sf16[(size_t)row * PROJ_DIM + c] = f2h(v);
      }
}

// ---------------------------------------------------------------------------
// sim_topk: sims = s_f16 @ mem_f16^T, single f16 MFMA, register-prefetch
// pipeline, fused per-row top-2 over the block's 128 heads.
// Tile 128 rows x 128 heads, BK=64, grid (128 headchunks, 16 rowblocks)
// so XCD = headchunk%8 -> per-XCD B working set = 1 MB (fits 4 MiB L2).
// 256 thr (4 waves, wave tile 64x64). partial[row][hchunk]={v1,h1,v2,h2}.
// ---------------------------------------------------------------------------
__global__ __launch_bounds__(256, 3) void sim_topk(
    const unsigned short* __restrict__ Af16,   // [2048][256]
    const unsigned short* __restrict__ Bf16,   // [16384][256]
    float4* __restrict__ partial)
{
  __shared__ __align__(16) unsigned short smA[128 * 64];  // 16 KB
  __shared__ __align__(16) unsigned short smB[128 * 64];  // 16 KB
  const int tid = threadIdx.x;
  const int lane = tid & 63, w = tid >> 6;
  const int quad = lane >> 4, col = lane & 15;
  const int wm = (w >> 1) * 64, wn = (w & 1) * 64;
  const int h0 = blockIdx.x * 128;
  const int m0 = blockIdx.y * 128;

  floatx4 acc[4][4];
#pragma unroll
  for (int i = 0; i < 4; ++i)
#pragma unroll
    for (int j = 0; j < 4; ++j) {
      acc[i][j][0] = 0.f; acc[i][j][1] = 0.f;
      acc[i][j][2] = 0.f; acc[i][j][3] = 0.f;
    }

  // granules: per matrix 1024 (128 rows x 8 slots x 8 halves); 4/thread each
  int rA[4], kA[4];
#pragma unroll
  for (int t = 0; t < 4; ++t) {
    int P = t * 256 + tid;
    rA[t] = P >> 3; kA[t] = (P & 7) ^ (rA[t] & 7);
  }

  float4 pa[4], pb[4];
  auto gload = [&](int kc) {
#pragma unroll
    for (int t = 0; t < 4; ++t)
      pa[t] = *(const float4*)(Af16 + (size_t)(m0 + rA[t]) * PROJ_DIM + kc + kA[t] * 8);
#pragma unroll
    for (int t = 0; t < 4; ++t)
      pb[t] = *(const float4*)(Bf16 + (size_t)(h0 + rA[t]) * PROJ_DIM + kc + kA[t] * 8);
  };
  auto swrite = [&]() {
#pragma unroll
    for (int t = 0; t < 4; ++t) {
      *(float4*)&smA[(t * 256 + tid) * 8] = pa[t];
      *(float4*)&smB[(t * 256 + tid) * 8] = pb[t];
    }
  };

  gload(0);
  swrite();
  __syncthreads();

  for (int it = 0; it < 4; ++it) {
    if (it < 3) gload((it + 1) * 64);
#pragma unroll
    for (int ks = 0; ks < 2; ++ks) {
      half8 a[4], bfr[4];
#pragma unroll
      for (int i = 0; i < 4; ++i) {
        int rr = wm + i * 16 + col;
        a[i] = *(const half8*)&smA[rr * 64 + (((ks * 4 + quad) ^ (rr & 7)) * 8)];
      }
#pragma unroll
      for (int j = 0; j < 4; ++j) {
        int rr = wn + j * 16 + col;
        bfr[j] = *(const half8*)&smB[rr * 64 + (((ks * 4 + quad) ^ (rr & 7)) * 8)];
      }
#pragma unroll
      for (int i = 0; i < 4; ++i)
#pragma unroll
        for (int j = 0; j < 4; ++j)
          acc[i][j] = __builtin_amdgcn_mfma_f32_16x16x32_f16(a[i], bfr[j], acc[i][j], 0, 0, 0);
    }
    __syncthreads();
    if (it < 3) { swrite(); __syncthreads(); }
  }

  // ---- epilogue: per-row top-2 over this block's 128 heads ----
  float4* lds_p = (float4*)smA;   // [128][2] float4 = 4 KB

#pragma unroll
  for (int i = 0; i < 4; ++i)
#pragma unroll
    for (int r = 0; r < 4; ++r) {
      float b1 = acc[i][0][r]; int h1 = h0 + wn + col;
      float b2 = -3.4e38f;     int h2 = h1;
#pragma unroll
      for (int j = 1; j < 4; ++j) {
        float v = acc[i][j][r]; int h = h0 + wn + j * 16 + col;
        if (v > b1) { b2 = b1; h2 = h1; b1 = v; h1 = h; }
        else if (v > b2) { b2 = v; h2 = h; }
      }
#pragma unroll
      for (int m = 1; m <= 8; m <<= 1) {
        float ob1 = __shfl_xor(b1, m); int oh1 = __shfl_xor(h1, m);
        float ob2 = __shfl_xor(b2, m); int oh2 = __shfl_xor(h2, m);
        if (ob1 > b1) {
          if (b1 > ob2) { b2 = b1;  h2 = h1;  }
          else          { b2 = ob2; h2 = oh2; }
          b1 = ob1; h1 = oh1;
        } else if (ob1 > b2) { b2 = ob1; h2 = oh1; }
      }
      if (col == 0) {
        int row = wm + i * 16 + quad * 4 + r;   // 0..127
        lds_p[row * 2 + (w & 1)] =
            make_float4(b1, __int_as_float(h1), b2, __int_as_float(h2));
      }
    }
  __syncthreads();

  if (tid < 128) {
    int row = tid;
    float4 px = lds_p[row * 2 + 0];
    float4 py = lds_p[row * 2 + 1];
    float b1 = px.x; int h1 = __float_as_int(px.y);
    float b2 = px.z; int h2 = __float_as_int(px.w);
    top2_ins(py.x, __float_as_int(py.y), b1, h1, b2, h2);
    top2_ins(py.z, __float_as_int(py.w), b1, h1, b2, h2);
    partial[(size_t)(m0 + row) * 128 + blockIdx.x] =
        make_float4(b1, __int_as_float(h1), b2, __int_as_float(h2));
  }
}

// ---------------------------------------------------------------------------
// finalize: merge 128 partials/row (256 candidates) -> global top-4, exact
// fp32 rescore of all 4, pick winner, gather logits row. 1 wave per row.
// ---------------------------------------------------------------------------
__global__ __launch_bounds__(64) void finalize(
    const float4* __restrict__ partial, const float* __restrict__ S,
    const float* __restrict__ Mem, const float* __restrict__ logits,
    float* __restrict__ out)
{
  const int row  = blockIdx.x;
  const int lane = threadIdx.x;

  float4 p0 = partial[(size_t)row * 128 + lane];
  float4 p1 = partial[(size_t)row * 128 + 64 + lane];
  float v[4] = {p0.x, p0.z, p1.x, p1.z};
  int   c[4] = {__float_as_int(p0.y), __float_as_int(p0.w),
                __float_as_int(p1.y), __float_as_int(p1.w)};

  int cand[4];
#pragma unroll
  for (int t = 0; t < 4; ++t) {
    float lv = v[0]; int lh = c[0];
#pragma unroll
    for (int q = 1; q < 4; ++q)
      if (v[q] > lv || (v[q] == lv && c[q] < lh)) { lv = v[q]; lh = c[q]; }
#pragma unroll
    for (int d = 32; d; d >>= 1) {
      float ov = __shfl_xor(lv, d); int oh = __shfl_xor(lh, d);
      if (ov > lv || (ov == lv && oh < lh)) { lv = ov; lh = oh; }
    }
    cand[t] = lh;
#pragma unroll
    for (int q = 0; q < 4; ++q)
      if (c[q] == lh) v[q] = -3.4e38f;
  }

  // exact fp32 rescore of the 4 candidates (lane owns 4 k's)
  float4 sv = ((const float4*)(S + (size_t)row * PROJ_DIM))[lane];
  float bestv = -3.4e38f; int besth = 0x7fffffff;
#pragma unroll
  for (int t = 0; t < 4; ++t) {
    float4 mv = ((const float4*)(Mem + (size_t)cand[t] * PROJ_DIM))[lane];
    float d = sv.x * mv.x + sv.y * mv.y + sv.z * mv.z + sv.w * mv.w;
#pragma unroll
    for (int s = 32; s; s >>= 1) d += __shfl_xor(d, s);
    if (d > bestv || (d == bestv && cand[t] < besth)) { bestv = d; besth = cand[t]; }
  }
  out[(size_t)row * ACT_DIM + lane] = logits[(size_t)besth * ACT_DIM + lane];
}

// ---------------------------------------------------------------------------
extern "C" void kernel_launch(void* const* d_in, const int* in_sizes, int n_in,
                              void* d_out, int out_size, void* d_ws, size_t ws_size,
                              hipStream_t stream) {
  const float* state  = (const float*)d_in[0]; // [2048, 512]
  const float* rp     = (const float*)d_in[1]; // [512, 256]
  const float* mem    = (const float*)d_in[2]; // [16384, 256]
  const float* logits = (const float*)d_in[3]; // [16384, 64]
  float* out = (float*)d_out;                  // [2048, 64]

  // workspace (16 MB):
  //   [0, 0.25)M  rpT_hi  [256][512] bf16
  //   [0.25,0.5)M rpT_mid
  //   [1, 9)M     mem_f16 [16384][256] f16
  //   [9, 11)M    s       [2048][256] fp32
  //   [11,12)M    s_f16   [2048][256] f16
  //   [12,16)M    partial [2048][128] float4
  char* ws = (char*)d_ws;
  unsigned short* rpT_hi  = (unsigned short*)(ws);
  unsigned short* rpT_mid = (unsigned short*)(ws + (256u << 10));
  unsigned short* mem_f16 = (unsigned short*)(ws + (1u  << 20));
  float*          s       = (float*)(ws + (9u  << 20));
  unsigned short* s_f16   = (unsigned short*)(ws + (11u << 20));
  float4*         part    = (float4*)(ws + (12u << 20));

  prep<<<2080, 256, 0, stream>>>(rp, mem, rpT_hi, rpT_mid, mem_f16);

  gemm_proj<<<dim3(32, 4), 256, 0, stream>>>(state, rpT_hi, rpT_mid, s, s_f16);

  sim_topk<<<dim3(128, 16), 256, 0, stream>>>(s_f16, mem_f16, part);

  finalize<<<BATCH, 64, 0, stream>>>(part, s, mem, logits, out);
}

// Round 7
// 194.778 us; speedup vs baseline: 1.0487x; 1.0487x over previous
//
#include <hip/hip_runtime.h>

#define BATCH    2048
#define FLAT_IN  512
#define PROJ_DIM 256
#define HEADS    16384
#define ACT_DIM  64

typedef __attribute__((ext_vector_type(8))) short short8;   // 8 bf16/f16 bits
typedef _Float16 half8 __attribute__((ext_vector_type(8))); // 8 f16 (4 VGPR)
typedef __attribute__((ext_vector_type(4))) float floatx4;  // MFMA C/D

__device__ __forceinline__ unsigned short f2bf(float x) {
  unsigned u = __float_as_uint(x);
  u += 0x7fff + ((u >> 16) & 1);
  return (unsigned short)(u >> 16);
}
__device__ __forceinline__ float bf2f(unsigned short b) {
  return __uint_as_float(((unsigned)b) << 16);
}
__device__ __forceinline__ unsigned short f2h(float x) {
  _Float16 h = (_Float16)x;   // RNE
  return __builtin_bit_cast(unsigned short, h);
}

__device__ __forceinline__ void top2_ins(float v, int h, float& b1, int& i1,
                                         float& b2, int& i2) {
  if (v > b1 || (v == b1 && h < i1)) { b2 = b1; i2 = i1; b1 = v; i1 = h; }
  else if (v > b2 || (v == b2 && h < i2)) { b2 = v; i2 = h; }
}

#define GLDS16(g, l)                                                          \
  __builtin_amdgcn_global_load_lds(                                           \
      (__attribute__((address_space(1))) void*)(void*)(g),                    \
      (__attribute__((address_space(3))) void*)(l), 16, 0, 0)

// ---------------------------------------------------------------------------
// prep (R5-proven): blockIdx partitioned
//   [0, 1024)    : split state [2048][512] -> st_hi/st_mid bf16
//   [1024, 1056) : transpose+split rp [512][256] -> rpT_hi/mid [256][512]
//   [1056, 3104) : mem [16384][256] fp32 -> mem_f16
// ---------------------------------------------------------------------------
__global__ __launch_bounds__(256) void prep(
    const float* __restrict__ state, const float* __restrict__ rp,
    const float* __restrict__ mem,
    unsigned short* __restrict__ st_hi, unsigned short* __restrict__ st_mid,
    unsigned short* __restrict__ rpT_hi, unsigned short* __restrict__ rpT_mid,
    unsigned short* __restrict__ mem_f16)
{
  const int tid = threadIdx.x;
  const int b = blockIdx.x;
  if (b < 1024) {
    int i = b * 256 + tid;
    float4 v = ((const float4*)state)[i];
    ushort4 h, m;
    h.x = f2bf(v.x); m.x = f2bf(v.x - bf2f(h.x));
    h.y = f2bf(v.y); m.y = f2bf(v.y - bf2f(h.y));
    h.z = f2bf(v.z); m.z = f2bf(v.z - bf2f(h.z));
    h.w = f2bf(v.w); m.w = f2bf(v.w - bf2f(h.w));
    ((ushort4*)st_hi)[i]  = h;
    ((ushort4*)st_mid)[i] = m;
  } else if (b < 1056) {
    __shared__ float t[64][65];
    int bid = b - 1024;
    int k0 = (bid >> 2) * 64, n0 = (bid & 3) * 64;
#pragma unroll
    for (int it = 0; it < 16; ++it) {
      int lin = it * 256 + tid;
      int kr = lin >> 6, nc = lin & 63;
      t[kr][nc] = rp[(size_t)(k0 + kr) * PROJ_DIM + n0 + nc];
    }
    __syncthreads();
#pragma unroll
    for (int it = 0; it < 16; ++it) {
      int lin = it * 256 + tid;
      int nr = lin >> 6, kc = lin & 63;
      float v = t[kc][nr];
      unsigned short hh = f2bf(v);
      rpT_hi [(size_t)(n0 + nr) * FLAT_IN + k0 + kc] = hh;
      rpT_mid[(size_t)(n0 + nr) * FLAT_IN + k0 + kc] = f2bf(v - bf2f(hh));
    }
  } else {
    int i2 = (b - 1056) * 256 + tid;          // 8-float granule index
    float4 x = ((const float4*)mem)[2 * i2];
    float4 y = ((const float4*)mem)[2 * i2 + 1];
    short8 o;
    o[0] = (short)f2h(x.x); o[1] = (short)f2h(x.y);
    o[2] = (short)f2h(x.z); o[3] = (short)f2h(x.w);
    o[4] = (short)f2h(y.x); o[5] = (short)f2h(y.y);
    o[6] = (short)f2h(y.z); o[7] = (short)f2h(y.w);
    ((short8*)mem_f16)[i2] = o;
  }
}

// ---------------------------------------------------------------------------
// gemm_proj (R5-proven): s = state @ rp via 3-term split-bf16 MFMA, GLDS
// staging. Tile 64x64, BK=64, grid (32,4), 256 thr. Writes s (fp32) + s_f16.
// ---------------------------------------------------------------------------
__global__ __launch_bounds__(256, 2) void gemm_proj(
    const unsigned short* __restrict__ Ahi, const unsigned short* __restrict__ Amid,
    const unsigned short* __restrict__ Bhi, const unsigned short* __restrict__ Bmid,
    float* __restrict__ S, unsigned short* __restrict__ Sf16)
{
  __shared__ __align__(16) unsigned short sm[4][64 * 64];
  const int tid = threadIdx.x;
  const int lane = tid & 63, w = tid >> 6;
  const int quad = lane >> 4, col = lane & 15;
  const int wm = (w >> 1) * 32, wn = (w & 1) * 32;
  const int m0 = blockIdx.x * 64, n0 = blockIdx.y * 64;

  floatx4 acc[2][2];
#pragma unroll
  for (int i = 0; i < 2; ++i)
#pragma unroll
    for (int j = 0; j < 2; ++j) {
      acc[i][j][0] = 0.f; acc[i][j][1] = 0.f;
      acc[i][j][2] = 0.f; acc[i][j][3] = 0.f;
    }

  const int P0 = tid, P1 = tid + 256;
  const int r0 = P0 >> 3, kl0 = (P0 & 7) ^ (r0 & 7);
  const int r1 = P1 >> 3, kl1 = (P1 & 7) ^ (r1 & 7);

  for (int kc = 0; kc < FLAT_IN; kc += 64) {
    GLDS16(Ahi  + (size_t)(m0 + r0) * FLAT_IN + kc + kl0 * 8, &sm[0][P0 * 8]);
    GLDS16(Ahi  + (size_t)(m0 + r1) * FLAT_IN + kc + kl1 * 8, &sm[0][P1 * 8]);
    GLDS16(Amid + (size_t)(m0 + r0) * FLAT_IN + kc + kl0 * 8, &sm[1][P0 * 8]);
    GLDS16(Amid + (size_t)(m0 + r1) * FLAT_IN + kc + kl1 * 8, &sm[1][P1 * 8]);
    GLDS16(Bhi  + (size_t)(n0 + r0) * FLAT_IN + kc + kl0 * 8, &sm[2][P0 * 8]);
    GLDS16(Bhi  + (size_t)(n0 + r1) * FLAT_IN + kc + kl1 * 8, &sm[2][P1 * 8]);
    GLDS16(Bmid + (size_t)(n0 + r0) * FLAT_IN + kc + kl0 * 8, &sm[3][P0 * 8]);
    GLDS16(Bmid + (size_t)(n0 + r1) * FLAT_IN + kc + kl1 * 8, &sm[3][P1 * 8]);
    __syncthreads();

#pragma unroll
    for (int ks = 0; ks < 2; ++ks) {
      short8 bf[2][2];
#pragma unroll
      for (int j = 0; j < 2; ++j) {
        int rr = wn + j * 16 + col;
        int off = rr * 64 + (((ks * 4 + quad) ^ (rr & 7)) * 8);
        bf[j][0] = *(const short8*)&sm[2][off];
        bf[j][1] = *(const short8*)&sm[3][off];
      }
#pragma unroll
      for (int i = 0; i < 2; ++i) {
        int rr = wm + i * 16 + col;
        int off = rr * 64 + (((ks * 4 + quad) ^ (rr & 7)) * 8);
        short8 a0 = *(const short8*)&sm[0][off];
        short8 a1 = *(const short8*)&sm[1][off];
#pragma unroll
        for (int j = 0; j < 2; ++j) {
          acc[i][j] = __builtin_amdgcn_mfma_f32_16x16x32_bf16(a0, bf[j][0], acc[i][j], 0, 0, 0);
          acc[i][j] = __builtin_amdgcn_mfma_f32_16x16x32_bf16(a0, bf[j][1], acc[i][j], 0, 0, 0);
          acc[i][j] = __builtin_amdgcn_mfma_f32_16x16x32_bf16(a1, bf[j][0], acc[i][j], 0, 0, 0);
        }
      }
    }
    __syncthreads();
  }

#pragma unroll
  for (int i = 0; i < 2; ++i)
#pragma unroll
    for (int j = 0; j < 2; ++j)
#pragma unroll
      for (int r = 0; r < 4; ++r) {
        int row = m0 + wm + i * 16 + quad * 4 + r;
        int c   = n0 + wn + j * 16 + col;
        float v = acc[i][j][r];
        S   [(size_t)row * PROJ_DIM + c] = v;
        Sf16[(size_t)row * PROJ_DIM + c] = f2h(v);
      }
}

// ---------------------------------------------------------------------------
// sim_topk: single-drain full-K tile. 128 rows x 128 heads x K=256 entirely
// in LDS (64+64 KB), one GLDS burst (32 granules/thread), ONE vmcnt drain,
// then 8 pure ds_read+MFMA steps, then per-row top-2 epilogue.
// grid (128 hchunks, 16 rowblocks) -> consecutive blocks differ in hchunk ->
// per-XCD B footprint = 16 chunks x 64 KB = 1 MB (L2-resident).
// 256 thr (4 waves, wave tile 64x64). partial[row][hchunk] = {v1,h1,v2,h2}.
// ---------------------------------------------------------------------------
__global__ __launch_bounds__(256, 1) void sim_topk(
    const unsigned short* __restrict__ Af16,   // [2048][256]
    const unsigned short* __restrict__ Bf16,   // [16384][256]
    float4* __restrict__ partial)
{
  __shared__ __align__(16) unsigned short smA[128 * 256];  // 64 KB
  __shared__ __align__(16) unsigned short smB[128 * 256];  // 64 KB
  const int tid = threadIdx.x;
  const int lane = tid & 63, w = tid >> 6;
  const int quad = lane >> 4, col = lane & 15;
  const int wm = (w >> 1) * 64, wn = (w & 1) * 64;
  const int h0 = blockIdx.x * 128;
  const int m0 = blockIdx.y * 128;

  // staging: 4096 granules (16B) per matrix; granule P: row = P>>5,
  // phys slot = P&31, logical k-slot = (P&31) ^ (row&31). 16 granules/thread
  // per matrix, all issued async before the single drain.
#pragma unroll
  for (int t = 0; t < 16; ++t) {
    int P = t * 256 + tid;
    int row = P >> 5;
    int sl  = (P & 31) ^ (row & 31);
    GLDS16(Af16 + (size_t)(m0 + row) * PROJ_DIM + sl * 8, &smA[P * 8]);
  }
#pragma unroll
  for (int t = 0; t < 16; ++t) {
    int P = t * 256 + tid;
    int row = P >> 5;
    int sl  = (P & 31) ^ (row & 31);
    GLDS16(Bf16 + (size_t)(h0 + row) * PROJ_DIM + sl * 8, &smB[P * 8]);
  }

  floatx4 acc[4][4];
#pragma unroll
  for (int i = 0; i < 4; ++i)
#pragma unroll
    for (int j = 0; j < 4; ++j) {
      acc[i][j][0] = 0.f; acc[i][j][1] = 0.f;
      acc[i][j][2] = 0.f; acc[i][j][3] = 0.f;
    }

  __syncthreads();   // the only vmcnt(0) drain

#pragma unroll
  for (int ks = 0; ks < 8; ++ks) {
    half8 a[4], bfr[4];
#pragma unroll
    for (int i = 0; i < 4; ++i) {
      int rr = wm + i * 16 + col;
      int phys = (ks * 4 + quad) ^ (rr & 31);
      a[i] = *(const half8*)&smA[rr * 256 + phys * 8];
    }
#pragma unroll
    for (int j = 0; j < 4; ++j) {
      int rr = wn + j * 16 + col;
      int phys = (ks * 4 + quad) ^ (rr & 31);
      bfr[j] = *(const half8*)&smB[rr * 256 + phys * 8];
    }
#pragma unroll
    for (int i = 0; i < 4; ++i)
#pragma unroll
      for (int j = 0; j < 4; ++j)
        acc[i][j] = __builtin_amdgcn_mfma_f32_16x16x32_f16(a[i], bfr[j], acc[i][j], 0, 0, 0);
  }
  __syncthreads();   // all LDS reads done before epilogue reuses smA

  // ---- epilogue: per-row top-2 over this block's 128 heads ----
  float4* lds_p = (float4*)smA;   // [128][2] float4 = 4 KB

#pragma unroll
  for (int i = 0; i < 4; ++i)
#pragma unroll
    for (int r = 0; r < 4; ++r) {
      float b1 = acc[i][0][r]; int h1 = h0 + wn + col;
      float b2 = -3.4e38f;     int h2 = h1;
#pragma unroll
      for (int j = 1; j < 4; ++j) {
        float v = acc[i][j][r]; int h = h0 + wn + j * 16 + col;
        if (v > b1) { b2 = b1; h2 = h1; b1 = v; h1 = h; }
        else if (v > b2) { b2 = v; h2 = h; }
      }
#pragma unroll
      for (int m = 1; m <= 8; m <<= 1) {
        float ob1 = __shfl_xor(b1, m); int oh1 = __shfl_xor(h1, m);
        float ob2 = __shfl_xor(b2, m); int oh2 = __shfl_xor(h2, m);
        if (ob1 > b1) {
          if (b1 > ob2) { b2 = b1;  h2 = h1;  }
          else          { b2 = ob2; h2 = oh2; }
          b1 = ob1; h1 = oh1;
        } else if (ob1 > b2) { b2 = ob1; h2 = oh1; }
      }
      if (col == 0) {
        int row = wm + i * 16 + quad * 4 + r;   // 0..127
        lds_p[row * 2 + (w & 1)] =
            make_float4(b1, __int_as_float(h1), b2, __int_as_float(h2));
      }
    }
  __syncthreads();

  if (tid < 128) {
    int row = tid;
    float4 px = lds_p[row * 2 + 0];
    float4 py = lds_p[row * 2 + 1];
    float b1 = px.x; int h1 = __float_as_int(px.y);
    float b2 = px.z; int h2 = __float_as_int(px.w);
    top2_ins(py.x, __float_as_int(py.y), b1, h1, b2, h2);
    top2_ins(py.z, __float_as_int(py.w), b1, h1, b2, h2);
    partial[(size_t)(m0 + row) * 128 + blockIdx.x] =
        make_float4(b1, __int_as_float(h1), b2, __int_as_float(h2));
  }
}

// ---------------------------------------------------------------------------
// finalize: merge 128 partials/row (256 candidates) -> global top-4, exact
// fp32 rescore of all 4, pick winner, gather logits row. 1 wave per row.
// ---------------------------------------------------------------------------
__global__ __launch_bounds__(64) void finalize(
    const float4* __restrict__ partial, const float* __restrict__ S,
    const float* __restrict__ Mem, const float* __restrict__ logits,
    float* __restrict__ out)
{
  const int row  = blockIdx.x;
  const int lane = threadIdx.x;

  float4 p0 = partial[(size_t)row * 128 + lane];
  float4 p1 = partial[(size_t)row * 128 + 64 + lane];
  float v[4] = {p0.x, p0.z, p1.x, p1.z};
  int   c[4] = {__float_as_int(p0.y), __float_as_int(p0.w),
                __float_as_int(p1.y), __float_as_int(p1.w)};

  int cand[4];
#pragma unroll
  for (int t = 0; t < 4; ++t) {
    float lv = v[0]; int lh = c[0];
#pragma unroll
    for (int q = 1; q < 4; ++q)
      if (v[q] > lv || (v[q] == lv && c[q] < lh)) { lv = v[q]; lh = c[q]; }
#pragma unroll
    for (int d = 32; d; d >>= 1) {
      float ov = __shfl_xor(lv, d); int oh = __shfl_xor(lh, d);
      if (ov > lv || (ov == lv && oh < lh)) { lv = ov; lh = oh; }
    }
    cand[t] = lh;
#pragma unroll
    for (int q = 0; q < 4; ++q)
      if (c[q] == lh) v[q] = -3.4e38f;
  }

  // exact fp32 rescore of the 4 candidates (lane owns 4 k's)
  float4 sv = ((const float4*)(S + (size_t)row * PROJ_DIM))[lane];
  float bestv = -3.4e38f; int besth = 0x7fffffff;
#pragma unroll
  for (int t = 0; t < 4; ++t) {
    float4 mv = ((const float4*)(Mem + (size_t)cand[t] * PROJ_DIM))[lane];
    float d = sv.x * mv.x + sv.y * mv.y + sv.z * mv.z + sv.w * mv.w;
#pragma unroll
    for (int s = 32; s; s >>= 1) d += __shfl_xor(d, s);
    if (d > bestv || (d == bestv && cand[t] < besth)) { bestv = d; besth = cand[t]; }
  }
  out[(size_t)row * ACT_DIM + lane] = logits[(size_t)besth * ACT_DIM + lane];
}

// ---------------------------------------------------------------------------
extern "C" void kernel_launch(void* const* d_in, const int* in_sizes, int n_in,
                              void* d_out, int out_size, void* d_ws, size_t ws_size,
                              hipStream_t stream) {
  const float* state  = (const float*)d_in[0]; // [2048, 512]
  const float* rp     = (const float*)d_in[1]; // [512, 256]
  const float* mem    = (const float*)d_in[2]; // [16384, 256]
  const float* logits = (const float*)d_in[3]; // [16384, 64]
  float* out = (float*)d_out;                  // [2048, 64]

  // workspace (24 MB):
  //   [0, 2)M     st_hi  [2048][512] bf16
  //   [2, 4)M     st_mid
  //   [4, 4.25)M  rpT_hi [256][512] bf16
  //   [4.25,4.5)M rpT_mid
  //   [8, 16)M    mem_f16 [16384][256] f16
  //   [16,18)M    s      [2048][256] fp32
  //   [18,19)M    s_f16  [2048][256] f16
  //   [20,24)M    partial [2048][128] float4
  char* ws = (char*)d_ws;
  unsigned short* st_hi   = (unsigned short*)(ws);
  unsigned short* st_mid  = (unsigned short*)(ws + (2u  << 20));
  unsigned short* rpT_hi  = (unsigned short*)(ws + (4u  << 20));
  unsigned short* rpT_mid = (unsigned short*)(ws + (4u  << 20) + (256u << 10));
  unsigned short* mem_f16 = (unsigned short*)(ws + (8u  << 20));
  float*          s       = (float*)(ws + (16u << 20));
  unsigned short* s_f16   = (unsigned short*)(ws + (18u << 20));
  float4*         part    = (float4*)(ws + (20u << 20));

  prep<<<3104, 256, 0, stream>>>(state, rp, mem, st_hi, st_mid,
                                 rpT_hi, rpT_mid, mem_f16);

  gemm_proj<<<dim3(32, 4), 256, 0, stream>>>(st_hi, st_mid, rpT_hi, rpT_mid,
                                             s, s_f16);

  sim_topk<<<dim3(128, 16), 256, 0, stream>>>(s_f16, mem_f16, part);

  finalize<<<BATCH, 64, 0, stream>>>(part, s, mem, logits, out);
}

// Round 8
// 190.854 us; speedup vs baseline: 1.0703x; 1.0206x over previous
//
#include <hip/hip_runtime.h>

#define BATCH    2048
#define FLAT_IN  512
#define PROJ_DIM 256
#define HEADS    16384
#define ACT_DIM  64

typedef __attribute__((ext_vector_type(8))) short short8;   // 8 bf16/f16 bits
typedef _Float16 half8 __attribute__((ext_vector_type(8))); // 8 f16 (4 VGPR)
typedef __attribute__((ext_vector_type(4))) float floatx4;  // MFMA C/D

__device__ __forceinline__ unsigned short f2bf(float x) {
  unsigned u = __float_as_uint(x);
  u += 0x7fff + ((u >> 16) & 1);
  return (unsigned short)(u >> 16);
}
__device__ __forceinline__ float bf2f(unsigned short b) {
  return __uint_as_float(((unsigned)b) << 16);
}
__device__ __forceinline__ unsigned short f2h(float x) {
  _Float16 h = (_Float16)x;   // RNE
  return __builtin_bit_cast(unsigned short, h);
}

#define GLDS16(g, l)                                                          \
  __builtin_amdgcn_global_load_lds(                                           \
      (__attribute__((address_space(1))) void*)(void*)(g),                    \
      (__attribute__((address_space(3))) void*)(l), 16, 0, 0)

// ---------------------------------------------------------------------------
// prep: ONLY the rp transpose+split now. 32 blocks.
// rp [512][256] fp32 -> rpT_hi/mid [256][512] bf16.
// ---------------------------------------------------------------------------
__global__ __launch_bounds__(256) void prep(
    const float* __restrict__ rp,
    unsigned short* __restrict__ rpT_hi, unsigned short* __restrict__ rpT_mid)
{
  __shared__ float t[64][65];
  const int tid = threadIdx.x;
  int bid = blockIdx.x;
  int k0 = (bid >> 2) * 64, n0 = (bid & 3) * 64;
#pragma unroll
  for (int it = 0; it < 16; ++it) {
    int lin = it * 256 + tid;
    int kr = lin >> 6, nc = lin & 63;
    t[kr][nc] = rp[(size_t)(k0 + kr) * PROJ_DIM + n0 + nc];
  }
  __syncthreads();
#pragma unroll
  for (int it = 0; it < 16; ++it) {
    int lin = it * 256 + tid;
    int nr = lin >> 6, kc = lin & 63;
    float v = t[kc][nr];
    unsigned short hh = f2bf(v);
    rpT_hi [(size_t)(n0 + nr) * FLAT_IN + k0 + kc] = hh;
    rpT_mid[(size_t)(n0 + nr) * FLAT_IN + k0 + kc] = f2bf(v - bf2f(hh));
  }
}

// ---------------------------------------------------------------------------
// gemm_proj: s = state @ rp via 3-term split-bf16 MFMA. A staged as RAW fp32
// through GLDS (no state-split prep pass); hi/mid split in VALU after LDS
// read. Tile 64x64, BK=64, grid (32,4), 256 thr (4 waves, wave 32x32).
// Epilogue writes s (fp32) + s_f16.
// ---------------------------------------------------------------------------
__global__ __launch_bounds__(256, 2) void gemm_proj(
    const float* __restrict__ state,
    const unsigned short* __restrict__ Bhi, const unsigned short* __restrict__ Bmid,
    float* __restrict__ S, unsigned short* __restrict__ Sf16)
{
  __shared__ __align__(16) float          smA [64 * 64];   // fp32, 16 KB
  __shared__ __align__(16) unsigned short smBh[64 * 64];   // 8 KB
  __shared__ __align__(16) unsigned short smBm[64 * 64];   // 8 KB
  const int tid = threadIdx.x;
  const int lane = tid & 63, w = tid >> 6;
  const int quad = lane >> 4, col = lane & 15;
  const int wm = (w >> 1) * 32, wn = (w & 1) * 32;
  const int m0 = blockIdx.x * 64, n0 = blockIdx.y * 64;

  floatx4 acc[2][2];
#pragma unroll
  for (int i = 0; i < 2; ++i)
#pragma unroll
    for (int j = 0; j < 2; ++j) {
      acc[i][j][0] = 0.f; acc[i][j][1] = 0.f;
      acc[i][j][2] = 0.f; acc[i][j][3] = 0.f;
    }

  // A fp32: 1024 granules (16B = 4 floats): row = P>>4, phys slot = P&15,
  //         logical k-slot = phys ^ (row&15). 4 granules/thread.
  // B bf16: 512 granules/plane: row = P>>3, phys = P&7, klog = phys^(row&7).
  const int PB0 = tid, PB1 = tid + 256;
  const int rb0 = PB0 >> 3, kb0 = (PB0 & 7) ^ (rb0 & 7);
  const int rb1 = PB1 >> 3, kb1 = (PB1 & 7) ^ (rb1 & 7);

  for (int kc = 0; kc < FLAT_IN; kc += 64) {
#pragma unroll
    for (int t = 0; t < 4; ++t) {
      int P = t * 256 + tid;
      int row = P >> 4;
      int klog = (P & 15) ^ (row & 15);
      GLDS16(state + (size_t)(m0 + row) * FLAT_IN + kc + klog * 4, &smA[P * 4]);
    }
    GLDS16(Bhi  + (size_t)(n0 + rb0) * FLAT_IN + kc + kb0 * 8, &smBh[PB0 * 8]);
    GLDS16(Bhi  + (size_t)(n0 + rb1) * FLAT_IN + kc + kb1 * 8, &smBh[PB1 * 8]);
    GLDS16(Bmid + (size_t)(n0 + rb0) * FLAT_IN + kc + kb0 * 8, &smBm[PB0 * 8]);
    GLDS16(Bmid + (size_t)(n0 + rb1) * FLAT_IN + kc + kb1 * 8, &smBm[PB1 * 8]);
    __syncthreads();

#pragma unroll
    for (int ks = 0; ks < 2; ++ks) {
      short8 bf[2][2];
#pragma unroll
      for (int j = 0; j < 2; ++j) {
        int rr = wn + j * 16 + col;
        int off = rr * 64 + (((ks * 4 + quad) ^ (rr & 7)) * 8);
        bf[j][0] = *(const short8*)&smBh[off];
        bf[j][1] = *(const short8*)&smBm[off];
      }
#pragma unroll
      for (int i = 0; i < 2; ++i) {
        int rr = wm + i * 16 + col;
        int s0 = ks * 8 + quad * 2;           // logical 4-float slot pair
        float4 f0 = *(const float4*)&smA[rr * 64 + ((s0     ^ (rr & 15)) * 4)];
        float4 f1 = *(const float4*)&smA[rr * 64 + (((s0+1) ^ (rr & 15)) * 4)];
        float f[8] = {f0.x, f0.y, f0.z, f0.w, f1.x, f1.y, f1.z, f1.w};
        short8 a0, a1;
#pragma unroll
        for (int q = 0; q < 8; ++q) {
          unsigned short hh = f2bf(f[q]);
          a0[q] = (short)hh;
          a1[q] = (short)f2bf(f[q] - bf2f(hh));
        }
#pragma unroll
        for (int j = 0; j < 2; ++j) {
          acc[i][j] = __builtin_amdgcn_mfma_f32_16x16x32_bf16(a0, bf[j][0], acc[i][j], 0, 0, 0);
          acc[i][j] = __builtin_amdgcn_mfma_f32_16x16x32_bf16(a0, bf[j][1], acc[i][j], 0, 0, 0);
          acc[i][j] = __builtin_amdgcn_mfma_f32_16x16x32_bf16(a1, bf[j][0], acc[i][j], 0, 0, 0);
        }
      }
    }
    __syncthreads();
  }

#pragma unroll
  for (int i = 0; i < 2; ++i)
#pragma unroll
    for (int j = 0; j < 2; ++j)
#pragma unroll
      for (int r = 0; r < 4; ++r) {
        int row = m0 + wm + i * 16 + quad * 4 + r;
        int c   = n0 + wn + j * 16 + col;
        float v = acc[i][j][r];
        S   [(size_t)row * PROJ_DIM + c] = v;
        Sf16[(size_t)row * PROJ_DIM + c] = f2h(v);
      }
}

// ---------------------------------------------------------------------------
// sim_topk: B-stationary streaming. Block owns 64 heads; B panel (64x256 f16,
// converted from fp32 mem during load) lives in 32 KB LDS for the whole
// kernel. 4 waves each stream 2 tiles of 64 rows, A-fragments loaded DIRECTLY
// from global s_f16 (1 MB, L2-resident) -- zero barriers in the main loop.
// grid (256 hblocks, 4 rowgroups) -> XCD = hblock%8, per-XCD mem = 2 MB (L2).
// Per wave-tile top-2 over the 64 heads -> partial[row][hblock].
// ---------------------------------------------------------------------------
__global__ __launch_bounds__(256, 4) void sim_topk(
    const unsigned short* __restrict__ Af16,   // s_f16 [2048][256]
    const float* __restrict__ Mem,             // [16384][256] fp32
    float4* __restrict__ partial)              // [2048][256]
{
  __shared__ __align__(16) unsigned short smB[64 * 256];  // 32 KB
  const int tid = threadIdx.x;
  const int lane = tid & 63, w = tid >> 6;
  const int quad = lane >> 4, col = lane & 15;
  const int h0 = blockIdx.x * 64;
  const int rbase = blockIdx.y * 512;

  // ---- one-time B panel: read fp32, convert to f16, swizzled ds_write ----
  // granule = 8 halves (16B); logical (head, slot): head = g>>5, slot = g&31;
  // phys = slot ^ (head & 31).
#pragma unroll
  for (int t = 0; t < 8; ++t) {
    int g = t * 256 + tid;
    int head = g >> 5, slot = g & 31;
    const float* src = Mem + (size_t)(h0 + head) * PROJ_DIM + slot * 8;
    float4 x = *(const float4*)src;
    float4 y = *(const float4*)(src + 4);
    short8 o;
    o[0] = (short)f2h(x.x); o[1] = (short)f2h(x.y);
    o[2] = (short)f2h(x.z); o[3] = (short)f2h(x.w);
    o[4] = (short)f2h(y.x); o[5] = (short)f2h(y.y);
    o[6] = (short)f2h(y.z); o[7] = (short)f2h(y.w);
    int phys = slot ^ (head & 31);
    *(short8*)&smB[(head * 32 + phys) * 8] = o;
  }
  __syncthreads();   // the only barrier

  for (int rt = 0; rt < 2; ++rt) {
    const int m0 = rbase + w * 128 + rt * 64;   // this wave's 64 rows

    floatx4 acc[4][4];
#pragma unroll
    for (int i = 0; i < 4; ++i)
#pragma unroll
      for (int j = 0; j < 4; ++j) {
        acc[i][j][0] = 0.f; acc[i][j][1] = 0.f;
        acc[i][j][2] = 0.f; acc[i][j][3] = 0.f;
      }

#pragma unroll
    for (int ks = 0; ks < 8; ++ks) {
      half8 a[4], b[4];
#pragma unroll
      for (int i = 0; i < 4; ++i) {
        int row = m0 + i * 16 + col;
        a[i] = *(const half8*)(Af16 + (size_t)row * PROJ_DIM + ks * 32 + quad * 8);
      }
#pragma unroll
      for (int j = 0; j < 4; ++j) {
        int head = j * 16 + col;
        int phys = (ks * 4 + quad) ^ (head & 31);
        b[j] = *(const half8*)&smB[(head * 32 + phys) * 8];
      }
#pragma unroll
      for (int i = 0; i < 4; ++i)
#pragma unroll
        for (int j = 0; j < 4; ++j)
          acc[i][j] = __builtin_amdgcn_mfma_f32_16x16x32_f16(a[i], b[j], acc[i][j], 0, 0, 0);
    }

    // ---- per-row top-2 over this block's 64 heads ----
#pragma unroll
    for (int i = 0; i < 4; ++i)
#pragma unroll
      for (int r = 0; r < 4; ++r) {
        float b1 = acc[i][0][r]; int h1 = h0 + col;
        float b2 = -3.4e38f;     int h2 = h1;
#pragma unroll
        for (int j = 1; j < 4; ++j) {
          float v = acc[i][j][r]; int h = h0 + j * 16 + col;
          if (v > b1) { b2 = b1; h2 = h1; b1 = v; h1 = h; }
          else if (v > b2) { b2 = v; h2 = h; }
        }
#pragma unroll
        for (int m = 1; m <= 8; m <<= 1) {
          float ob1 = __shfl_xor(b1, m); int oh1 = __shfl_xor(h1, m);
          float ob2 = __shfl_xor(b2, m); int oh2 = __shfl_xor(h2, m);
          if (ob1 > b1) {
            if (b1 > ob2) { b2 = b1;  h2 = h1;  }
            else          { b2 = ob2; h2 = oh2; }
            b1 = ob1; h1 = oh1;
          } else if (ob1 > b2) { b2 = ob1; h2 = oh1; }
        }
        if (col == 0) {
          int row = m0 + i * 16 + quad * 4 + r;
          partial[(size_t)row * 256 + blockIdx.x] =
              make_float4(b1, __int_as_float(h1), b2, __int_as_float(h2));
        }
      }
  }
}

// ---------------------------------------------------------------------------
// finalize: merge 256 partials/row (512 candidates) -> global top-4, exact
// fp32 rescore of all 4, pick winner, gather logits row. 1 wave per row.
// ---------------------------------------------------------------------------
__global__ __launch_bounds__(64) void finalize(
    const float4* __restrict__ partial, const float* __restrict__ S,
    const float* __restrict__ Mem, const float* __restrict__ logits,
    float* __restrict__ out)
{
  const int row  = blockIdx.x;
  const int lane = threadIdx.x;

  float v[8]; int c[8];
#pragma unroll
  for (int t = 0; t < 4; ++t) {
    float4 p = partial[(size_t)row * 256 + t * 64 + lane];
    v[2 * t]     = p.x; c[2 * t]     = __float_as_int(p.y);
    v[2 * t + 1] = p.z; c[2 * t + 1] = __float_as_int(p.w);
  }

  int cand[4];
#pragma unroll
  for (int t = 0; t < 4; ++t) {
    float lv = v[0]; int lh = c[0];
#pragma unroll
    for (int q = 1; q < 8; ++q)
      if (v[q] > lv || (v[q] == lv && c[q] < lh)) { lv = v[q]; lh = c[q]; }
#pragma unroll
    for (int d = 32; d; d >>= 1) {
      float ov = __shfl_xor(lv, d); int oh = __shfl_xor(lh, d);
      if (ov > lv || (ov == lv && oh < lh)) { lv = ov; lh = oh; }
    }
    cand[t] = lh;
#pragma unroll
    for (int q = 0; q < 8; ++q)
      if (c[q] == lh) v[q] = -3.4e38f;
  }

  // exact fp32 rescore of the 4 candidates (lane owns 4 k's)
  float4 sv = ((const float4*)(S + (size_t)row * PROJ_DIM))[lane];
  float bestv = -3.4e38f; int besth = 0x7fffffff;
#pragma unroll
  for (int t = 0; t < 4; ++t) {
    float4 mv = ((const float4*)(Mem + (size_t)cand[t] * PROJ_DIM))[lane];
    float d = sv.x * mv.x + sv.y * mv.y + sv.z * mv.z + sv.w * mv.w;
#pragma unroll
    for (int s = 32; s; s >>= 1) d += __shfl_xor(d, s);
    if (d > bestv || (d == bestv && cand[t] < besth)) { bestv = d; besth = cand[t]; }
  }
  out[(size_t)row * ACT_DIM + lane] = logits[(size_t)besth * ACT_DIM + lane];
}

// ---------------------------------------------------------------------------
extern "C" void kernel_launch(void* const* d_in, const int* in_sizes, int n_in,
                              void* d_out, int out_size, void* d_ws, size_t ws_size,
                              hipStream_t stream) {
  const float* state  = (const float*)d_in[0]; // [2048, 512]
  const float* rp     = (const float*)d_in[1]; // [512, 256]
  const float* mem    = (const float*)d_in[2]; // [16384, 256]
  const float* logits = (const float*)d_in[3]; // [16384, 64]
  float* out = (float*)d_out;                  // [2048, 64]

  // workspace (~12 MB):
  //   [0, 0.25)M   rpT_hi  [256][512] bf16
  //   [0.25, 0.5)M rpT_mid
  //   [1, 3)M      s       [2048][256] fp32
  //   [3, 4)M      s_f16   [2048][256] f16
  //   [4, 12)M     partial [2048][256] float4
  char* ws = (char*)d_ws;
  unsigned short* rpT_hi  = (unsigned short*)(ws);
  unsigned short* rpT_mid = (unsigned short*)(ws + (256u << 10));
  float*          s       = (float*)(ws + (1u  << 20));
  unsigned short* s_f16   = (unsigned short*)(ws + (3u  << 20));
  float4*         part    = (float4*)(ws + (4u  << 20));

  prep<<<32, 256, 0, stream>>>(rp, rpT_hi, rpT_mid);

  gemm_proj<<<dim3(32, 4), 256, 0, stream>>>(state, rpT_hi, rpT_mid, s, s_f16);

  sim_topk<<<dim3(256, 4), 256, 0, stream>>>(s_f16, mem, part);

  finalize<<<BATCH, 64, 0, stream>>>(part, s, mem, logits, out);
}

// Round 10
// 183.711 us; speedup vs baseline: 1.1119x; 1.0389x over previous
//
#include <hip/hip_runtime.h>

#define BATCH    2048
#define FLAT_IN  512
#define PROJ_DIM 256
#define HEADS    16384
#define ACT_DIM  64

typedef __attribute__((ext_vector_type(8))) short short8;   // 8 bf16/f16 bits
typedef _Float16 half8 __attribute__((ext_vector_type(8))); // 8 f16 (4 VGPR)
typedef __attribute__((ext_vector_type(4))) float floatx4;  // MFMA C/D

__device__ __forceinline__ unsigned short f2bf(float x) {
  unsigned u = __float_as_uint(x);
  u += 0x7fff + ((u >> 16) & 1);
  return (unsigned short)(u >> 16);
}
__device__ __forceinline__ float bf2f(unsigned short b) {
  return __uint_as_float(((unsigned)b) << 16);
}
__device__ __forceinline__ unsigned short f2h(float x) {
  _Float16 h = (_Float16)x;   // RNE
  return __builtin_bit_cast(unsigned short, h);
}

__device__ __forceinline__ void top2_ins(float v, int h, float& b1, int& i1,
                                         float& b2, int& i2) {
  if (v > b1 || (v == b1 && h < i1)) { b2 = b1; i2 = i1; b1 = v; i1 = h; }
  else if (v > b2 || (v == b2 && h < i2)) { b2 = v; i2 = h; }
}

#define GLDS16(g, l)                                                          \
  __builtin_amdgcn_global_load_lds(                                           \
      (__attribute__((address_space(1))) void*)(void*)(g),                    \
      (__attribute__((address_space(3))) void*)(l), 16, 0, 0)

// ---------------------------------------------------------------------------
// gemm_proj: s = state @ rp via 3-term split-bf16 MFMA. Fully self-contained:
// state fp32 and rp fp32 (k-major) are converted/transposed into LDS panels
// in-kernel (VALU cvt + ds_write). Tile 64x64, BK=64, grid (32,4), 256 thr.
// Writes s (fp32) + s_f16. No prep kernel needed.
// ---------------------------------------------------------------------------
__global__ __launch_bounds__(256, 2) void gemm_proj(
    const float* __restrict__ state,   // [2048][512]
    const float* __restrict__ rp,      // [512][256]
    float* __restrict__ S, unsigned short* __restrict__ Sf16)
{
  __shared__ __align__(16) unsigned short smAh[64 * 64];
  __shared__ __align__(16) unsigned short smAm[64 * 64];
  __shared__ __align__(16) unsigned short smBh[64 * 64];
  __shared__ __align__(16) unsigned short smBm[64 * 64];
  const int tid = threadIdx.x;
  const int lane = tid & 63, w = tid >> 6;
  const int quad = lane >> 4, col = lane & 15;
  const int wm = (w >> 1) * 32, wn = (w & 1) * 32;
  const int m0 = blockIdx.x * 64, n0 = blockIdx.y * 64;
  const int srow = lane;          // staging row (A) / col n (B)
  const int kgrp = w;             // 0..3

  floatx4 acc[2][2];
#pragma unroll
  for (int i = 0; i < 2; ++i)
#pragma unroll
    for (int j = 0; j < 2; ++j) {
      acc[i][j][0] = 0.f; acc[i][j][1] = 0.f;
      acc[i][j][2] = 0.f; acc[i][j][3] = 0.f;
    }

  for (int kc = 0; kc < FLAT_IN; kc += 64) {
    // ---- stage A: state rows, fp32 -> bf16 hi/mid, swizzled ds_write ----
#pragma unroll
    for (int h = 0; h < 2; ++h) {
      int k8 = kgrp + h * 4;                    // 16B k-granule 0..7
      const float* g = state + (size_t)(m0 + srow) * FLAT_IN + kc + k8 * 8;
      float4 x = *(const float4*)g;
      float4 y = *(const float4*)(g + 4);
      float f[8] = {x.x, x.y, x.z, x.w, y.x, y.y, y.z, y.w};
      short8 vh, vm;
#pragma unroll
      for (int q = 0; q < 8; ++q) {
        unsigned short hh = f2bf(f[q]);
        vh[q] = (short)hh; vm[q] = (short)f2bf(f[q] - bf2f(hh));
      }
      int phys = k8 ^ (srow & 7);
      *(short8*)&smAh[srow * 64 + phys * 8] = vh;
      *(short8*)&smAm[srow * 64 + phys * 8] = vm;
    }
    // ---- stage B: rp cols (transpose via strided-coalesced gather) ----
#pragma unroll
    for (int h = 0; h < 2; ++h) {
      int k8 = kgrp + h * 4;
      float f[8];
#pragma unroll
      for (int q = 0; q < 8; ++q)
        f[q] = rp[(size_t)(kc + k8 * 8 + q) * PROJ_DIM + n0 + srow];
      short8 vh, vm;
#pragma unroll
      for (int q = 0; q < 8; ++q) {
        unsigned short hh = f2bf(f[q]);
        vh[q] = (short)hh; vm[q] = (short)f2bf(f[q] - bf2f(hh));
      }
      int phys = k8 ^ (srow & 7);
      *(short8*)&smBh[srow * 64 + phys * 8] = vh;
      *(short8*)&smBm[srow * 64 + phys * 8] = vm;
    }
    __syncthreads();

#pragma unroll
    for (int ks = 0; ks < 2; ++ks) {
      short8 bh[2], bm[2];
#pragma unroll
      for (int j = 0; j < 2; ++j) {
        int rr = wn + j * 16 + col;
        int off = rr * 64 + (((ks * 4 + quad) ^ (rr & 7)) * 8);
        bh[j] = *(const short8*)&smBh[off];
        bm[j] = *(const short8*)&smBm[off];
      }
#pragma unroll
      for (int i = 0; i < 2; ++i) {
        int rr = wm + i * 16 + col;
        int off = rr * 64 + (((ks * 4 + quad) ^ (rr & 7)) * 8);
        short8 a0 = *(const short8*)&smAh[off];
        short8 a1 = *(const short8*)&smAm[off];
#pragma unroll
        for (int j = 0; j < 2; ++j) {
          acc[i][j] = __builtin_amdgcn_mfma_f32_16x16x32_bf16(a0, bh[j], acc[i][j], 0, 0, 0);
          acc[i][j] = __builtin_amdgcn_mfma_f32_16x16x32_bf16(a0, bm[j], acc[i][j], 0, 0, 0);
          acc[i][j] = __builtin_amdgcn_mfma_f32_16x16x32_bf16(a1, bh[j], acc[i][j], 0, 0, 0);
        }
      }
    }
    __syncthreads();
  }

#pragma unroll
  for (int i = 0; i < 2; ++i)
#pragma unroll
    for (int j = 0; j < 2; ++j)
#pragma unroll
      for (int r = 0; r < 4; ++r) {
        int row = m0 + wm + i * 16 + quad * 4 + r;
        int c   = n0 + wn + j * 16 + col;
        float v = acc[i][j][r];
        S   [(size_t)row * PROJ_DIM + c] = v;
        Sf16[(size_t)row * PROJ_DIM + c] = f2h(v);
      }
}

// ---------------------------------------------------------------------------
// sim_topk: one 1024-thr block per CU (16 waves = 4/SIMD from ONE block).
// LDS: B panel 128 heads x K=256 f16 (64 KB, converted from fp32 in-kernel)
// + A double-buffer 2 x (512 rows x 32 k) f16 (2x32 KB). Per superstep:
// stage B once; 8-iter K-loop with GLDS prefetch of chunk k+1 issued BEFORE
// computing chunk k -> the barrier drain lands after ~1300 cyc of compute.
// Each block does 2 supersteps; s = 2*bid+ss -> rowgroup = s>>7 (512 rows),
// headchunk = s&127 (128 heads). XCD = bid%8 -> headchunk sets disjoint
// across XCDs (mem read once from HBM, L2-reused x4).
// Wave tile 64x64 (wave grid 8x2). partial[row][hc] = {v1,h1,v2,h2}.
// ---------------------------------------------------------------------------
__global__ __launch_bounds__(1024, 4) void sim_topk(
    const unsigned short* __restrict__ Af16,   // s_f16 [2048][256]
    const float* __restrict__ Mem,             // [16384][256] fp32
    float4* __restrict__ partial)              // [2048][128]
{
  __shared__ __align__(16) unsigned short smB[128 * 256];    // 64 KB
  __shared__ __align__(16) unsigned short smA[2][512 * 32];  // 2 x 32 KB
  const int tid  = threadIdx.x;                // 0..1023
  const int lane = tid & 63, w = tid >> 6;     // w 0..15
  const int quad = lane >> 4, col = lane & 15;
  const int wrow = w >> 1, wcol = w & 1;       // 8 x 2 wave grid

  const int bhead = tid & 127;                 // B staging: head
  const int bsg   = tid >> 7;                  // B staging: slot group 0..7

  for (int ss = 0; ss < 2; ++ss) {
    const int s  = blockIdx.x * 2 + ss;        // [0,512)
    const int rg = s >> 7;                     // rowgroup [0,4)
    const int hc = s & 127;                    // headchunk [0,128)
    const unsigned short* Ab = Af16 + (size_t)rg * 512 * PROJ_DIM;
    const float* Mb = Mem + (size_t)hc * 128 * PROJ_DIM;

    // ---- stage B: fp32 -> f16, swizzled ds_write (phys = slot^(head&31)) --
#pragma unroll
    for (int t = 0; t < 4; ++t) {
      int slot = bsg * 4 + t;                  // 0..31
      const float* g = Mb + (size_t)bhead * PROJ_DIM + slot * 8;
      float4 x = *(const float4*)g;
      float4 y = *(const float4*)(g + 4);
      short8 o;
      o[0] = (short)f2h(x.x); o[1] = (short)f2h(x.y);
      o[2] = (short)f2h(x.z); o[3] = (short)f2h(x.w);
      o[4] = (short)f2h(y.x); o[5] = (short)f2h(y.y);
      o[6] = (short)f2h(y.z); o[7] = (short)f2h(y.w);
      int phys = slot ^ (bhead & 31);
      *(short8*)&smB[bhead * 256 + phys * 8] = o;
    }
    // ---- stage A chunk 0 (GLDS, swizzle folded into global index) ----
#pragma unroll
    for (int t = 0; t < 2; ++t) {
      int Q = t * 1024 + tid;                  // [0,2048)
      int row = Q >> 2, phys = Q & 3;
      int slot = phys ^ ((row ^ (row >> 2)) & 3);
      GLDS16(Ab + (size_t)row * PROJ_DIM + slot * 8, &smA[0][Q * 8]);
    }

    floatx4 acc[4][4];
#pragma unroll
    for (int i = 0; i < 4; ++i)
#pragma unroll
      for (int j = 0; j < 4; ++j) {
        acc[i][j][0] = 0.f; acc[i][j][1] = 0.f;
        acc[i][j][2] = 0.f; acc[i][j][3] = 0.f;
      }
    __syncthreads();   // B panel + A chunk 0 ready

    for (int kc = 0; kc < 8; ++kc) {
      // prefetch next A chunk FIRST -> ~full compute phase to land
      if (kc < 7) {
#pragma unroll
        for (int t = 0; t < 2; ++t) {
          int Q = t * 1024 + tid;
          int row = Q >> 2, phys = Q & 3;
          int slot = phys ^ ((row ^ (row >> 2)) & 3);
          GLDS16(Ab + (size_t)row * PROJ_DIM + (kc + 1) * 32 + slot * 8,
                 &smA[(kc + 1) & 1][Q * 8]);
        }
      }
      const unsigned short* bufA = smA[kc & 1];
      half8 a[4];
#pragma unroll
      for (int i = 0; i < 4; ++i) {
        int row = wrow * 64 + i * 16 + col;
        int phys = quad ^ ((row ^ (row >> 2)) & 3);
        a[i] = *(const half8*)&bufA[row * 32 + phys * 8];
      }
#pragma unroll
      for (int j = 0; j < 4; ++j) {
        int hrow = wcol * 64 + j * 16 + col;
        int phys = (kc * 4 + quad) ^ (hrow & 31);
        half8 b = *(const half8*)&smB[hrow * 256 + phys * 8];
#pragma unroll
        for (int i = 0; i < 4; ++i)
          acc[i][j] = __builtin_amdgcn_mfma_f32_16x16x32_f16(a[i], b, acc[i][j], 0, 0, 0);
      }
      __syncthreads();   // publishes prefetched chunk; drain mostly hidden
    }

    // ---- epilogue: per-row top-2 over this superstep's 128 heads ----
    float4* lds_p = (float4*)&smA[0][0];       // [512][2] float4 = 16 KB
    const int h0 = hc * 128;
#pragma unroll
    for (int i = 0; i < 4; ++i)
#pragma unroll
      for (int r = 0; r < 4; ++r) {
        float b1 = acc[i][0][r]; int h1 = h0 + wcol * 64 + col;
        float b2 = -3.4e38f;     int h2 = h1;
#pragma unroll
        for (int j = 1; j < 4; ++j) {
          float v = acc[i][j][r]; int h = h0 + wcol * 64 + j * 16 + col;
          if (v > b1) { b2 = b1; h2 = h1; b1 = v; h1 = h; }
          else if (v > b2) { b2 = v; h2 = h; }
        }
#pragma unroll
        for (int m = 1; m <= 8; m <<= 1) {
          float ob1 = __shfl_xor(b1, m); int oh1 = __shfl_xor(h1, m);
          float ob2 = __shfl_xor(b2, m); int oh2 = __shfl_xor(h2, m);
          if (ob1 > b1) {
            if (b1 > ob2) { b2 = b1;  h2 = h1;  }
            else          { b2 = ob2; h2 = oh2; }
            b1 = ob1; h1 = oh1;
          } else if (ob1 > b2) { b2 = ob1; h2 = oh1; }
        }
        if (col == 0) {
          int rowloc = wrow * 64 + i * 16 + quad * 4 + r;   // [0,512)
          lds_p[rowloc * 2 + wcol] =
              make_float4(b1, __int_as_float(h1), b2, __int_as_float(h2));
        }
      }
    __syncthreads();

    if (tid < 512) {
      float4 px = lds_p[tid * 2 + 0];
      float4 py = lds_p[tid * 2 + 1];
      float b1 = px.x; int h1 = __float_as_int(px.y);
      float b2 = px.z; int h2 = __float_as_int(px.w);
      top2_ins(py.x, __float_as_int(py.y), b1, h1, b2, h2);
      top2_ins(py.z, __float_as_int(py.w), b1, h1, b2, h2);
      partial[(size_t)(rg * 512 + tid) * 128 + hc] =
          make_float4(b1, __int_as_float(h1), b2, __int_as_float(h2));
    }
    __syncthreads();   // lds_p reads done before next superstep re-stages
  }
}

// ---------------------------------------------------------------------------
// finalize: merge 128 partials/row (256 candidates) -> global top-4, exact
// fp32 rescore of all 4, pick winner, gather logits row. 1 wave per row.
// ---------------------------------------------------------------------------
__global__ __launch_bounds__(64) void finalize(
    const float4* __restrict__ partial, const float* __restrict__ S,
    const float* __restrict__ Mem, const float* __restrict__ logits,
    float* __restrict__ out)
{
  const int row  = blockIdx.x;
  const int lane = threadIdx.x;

  float4 p0 = partial[(size_t)row * 128 + lane];
  float4 p1 = partial[(size_t)row * 128 + 64 + lane];
  float v[4] = {p0.x, p0.z, p1.x, p1.z};
  int   c[4] = {__float_as_int(p0.y), __float_as_int(p0.w),
                __float_as_int(p1.y), __float_as_int(p1.w)};

  int cand[4];
#pragma unroll
  for (int t = 0; t < 4; ++t) {
    float lv = v[0]; int lh = c[0];
#pragma unroll
    for (int q = 1; q < 4; ++q)
      if (v[q] > lv || (v[q] == lv && c[q] < lh)) { lv = v[q]; lh = c[q]; }
#pragma unroll
    for (int d = 32; d; d >>= 1) {
      float ov = __shfl_xor(lv, d); int oh = __shfl_xor(lh, d);
      if (ov > lv || (ov == lv && oh < lh)) { lv = ov; lh = oh; }
    }
    cand[t] = lh;
#pragma unroll
    for (int q = 0; q < 4; ++q)
      if (c[q] == lh) v[q] = -3.4e38f;
  }

  // exact fp32 rescore of the 4 candidates (lane owns 4 k's)
  float4 sv = ((const float4*)(S + (size_t)row * PROJ_DIM))[lane];
  float bestv = -3.4e38f; int besth = 0x7fffffff;
#pragma unroll
  for (int t = 0; t < 4; ++t) {
    float4 mv = ((const float4*)(Mem + (size_t)cand[t] * PROJ_DIM))[lane];
    float d = sv.x * mv.x + sv.y * mv.y + sv.z * mv.z + sv.w * mv.w;
#pragma unroll
    for (int s = 32; s; s >>= 1) d += __shfl_xor(d, s);
    if (d > bestv || (d == bestv && cand[t] < besth)) { bestv = d; besth = cand[t]; }
  }
  out[(size_t)row * ACT_DIM + lane] = logits[(size_t)besth * ACT_DIM + lane];
}

// ---------------------------------------------------------------------------
extern "C" void kernel_launch(void* const* d_in, const int* in_sizes, int n_in,
                              void* d_out, int out_size, void* d_ws, size_t ws_size,
                              hipStream_t stream) {
  const float* state  = (const float*)d_in[0]; // [2048, 512]
  const float* rp     = (const float*)d_in[1]; // [512, 256]
  const float* mem    = (const float*)d_in[2]; // [16384, 256]
  const float* logits = (const float*)d_in[3]; // [16384, 64]
  float* out = (float*)d_out;                  // [2048, 64]

  // workspace (8 MB):
  //   [0, 2)M  s       [2048][256] fp32
  //   [2, 3)M  s_f16   [2048][256] f16
  //   [4, 8)M  partial [2048][128] float4
  char* ws = (char*)d_ws;
  float*          s     = (float*)(ws);
  unsigned short* s_f16 = (unsigned short*)(ws + (2u << 20));
  float4*         part  = (float4*)(ws + (4u << 20));

  gemm_proj<<<dim3(32, 4), 256, 0, stream>>>(state, rp, s, s_f16);

  sim_topk<<<256, 1024, 0, stream>>>(s_f16, mem, part);

  finalize<<<BATCH, 64, 0, stream>>>(part, s, mem, logits, out);
}

// Round 11
// 120.712 us; speedup vs baseline: 1.6922x; 1.5219x over previous
//
#include <hip/hip_runtime.h>

#define BATCH    2048
#define FLAT_IN  512
#define PROJ_DIM 256
#define HEADS    16384
#define ACT_DIM  64

typedef __attribute__((ext_vector_type(8))) short short8;   // 8 bf16/f16 bits
typedef _Float16 half8 __attribute__((ext_vector_type(8))); // 8 f16 (4 VGPR)
typedef __attribute__((ext_vector_type(4))) float floatx4;  // MFMA C/D

__device__ __forceinline__ unsigned short f2bf(float x) {
  unsigned u = __float_as_uint(x);
  u += 0x7fff + ((u >> 16) & 1);
  return (unsigned short)(u >> 16);
}
__device__ __forceinline__ float bf2f(unsigned short b) {
  return __uint_as_float(((unsigned)b) << 16);
}
__device__ __forceinline__ unsigned short f2h(float x) {
  _Float16 h = (_Float16)x;   // RNE
  return __builtin_bit_cast(unsigned short, h);
}

#define GLDS16(g, l)                                                          \
  __builtin_amdgcn_global_load_lds(                                           \
      (__attribute__((address_space(1))) void*)(void*)(g),                    \
      (__attribute__((address_space(3))) void*)(l), 16, 0, 0)

// ---------------------------------------------------------------------------
// prep: [0,1024) split state -> st_hi/st_mid bf16; [1024,1056) transpose+
// split rp -> rpT_hi/mid. (mem conversion moved into gemm_conv launch.)
// ---------------------------------------------------------------------------
__global__ __launch_bounds__(256) void prep(
    const float* __restrict__ state, const float* __restrict__ rp,
    unsigned short* __restrict__ st_hi, unsigned short* __restrict__ st_mid,
    unsigned short* __restrict__ rpT_hi, unsigned short* __restrict__ rpT_mid)
{
  const int tid = threadIdx.x;
  const int b = blockIdx.x;
  if (b < 1024) {
    int i = b * 256 + tid;
    float4 v = ((const float4*)state)[i];
    ushort4 h, m;
    h.x = f2bf(v.x); m.x = f2bf(v.x - bf2f(h.x));
    h.y = f2bf(v.y); m.y = f2bf(v.y - bf2f(h.y));
    h.z = f2bf(v.z); m.z = f2bf(v.z - bf2f(h.z));
    h.w = f2bf(v.w); m.w = f2bf(v.w - bf2f(h.w));
    ((ushort4*)st_hi)[i]  = h;
    ((ushort4*)st_mid)[i] = m;
  } else {
    __shared__ float t[64][65];
    int bid = b - 1024;
    int k0 = (bid >> 2) * 64, n0 = (bid & 3) * 64;
#pragma unroll
    for (int it = 0; it < 16; ++it) {
      int lin = it * 256 + tid;
      int kr = lin >> 6, nc = lin & 63;
      t[kr][nc] = rp[(size_t)(k0 + kr) * PROJ_DIM + n0 + nc];
    }
    __syncthreads();
#pragma unroll
    for (int it = 0; it < 16; ++it) {
      int lin = it * 256 + tid;
      int nr = lin >> 6, kc = lin & 63;
      float v = t[kc][nr];
      unsigned short hh = f2bf(v);
      rpT_hi [(size_t)(n0 + nr) * FLAT_IN + k0 + kc] = hh;
      rpT_mid[(size_t)(n0 + nr) * FLAT_IN + k0 + kc] = f2bf(v - bf2f(hh));
    }
  }
}

// ---------------------------------------------------------------------------
// gemm_conv: blocks [0,128) = R5-proven gemm_proj (s = state @ rp, 3-term
// split-bf16 MFMA, GLDS staging, tile 64x64, BK=64); blocks [128,2176) =
// mem fp32 -> f16 conversion (fills the CUs gemm leaves idle).
// ---------------------------------------------------------------------------
__global__ __launch_bounds__(256, 2) void gemm_conv(
    const unsigned short* __restrict__ Ahi, const unsigned short* __restrict__ Amid,
    const unsigned short* __restrict__ Bhi, const unsigned short* __restrict__ Bmid,
    const float* __restrict__ mem,
    float* __restrict__ S, unsigned short* __restrict__ Sf16,
    unsigned short* __restrict__ mem_f16)
{
  const int tid = threadIdx.x;
  if (blockIdx.x >= 128) {
    // ---- conversion path ----
    int i2 = (blockIdx.x - 128) * 256 + tid;   // 8-float granule index
    float4 x = ((const float4*)mem)[2 * i2];
    float4 y = ((const float4*)mem)[2 * i2 + 1];
    short8 o;
    o[0] = (short)f2h(x.x); o[1] = (short)f2h(x.y);
    o[2] = (short)f2h(x.z); o[3] = (short)f2h(x.w);
    o[4] = (short)f2h(y.x); o[5] = (short)f2h(y.y);
    o[6] = (short)f2h(y.z); o[7] = (short)f2h(y.w);
    ((short8*)mem_f16)[i2] = o;
    return;
  }

  // ---- gemm path (R5-proven body) ----
  __shared__ __align__(16) unsigned short sm[4][64 * 64];
  const int lane = tid & 63, w = tid >> 6;
  const int quad = lane >> 4, col = lane & 15;
  const int wm = (w >> 1) * 32, wn = (w & 1) * 32;
  const int g = blockIdx.x;
  const int m0 = (g & 31) * 64, n0 = (g >> 5) * 64;

  floatx4 acc[2][2];
#pragma unroll
  for (int i = 0; i < 2; ++i)
#pragma unroll
    for (int j = 0; j < 2; ++j) {
      acc[i][j][0] = 0.f; acc[i][j][1] = 0.f;
      acc[i][j][2] = 0.f; acc[i][j][3] = 0.f;
    }

  const int P0 = tid, P1 = tid + 256;
  const int r0 = P0 >> 3, kl0 = (P0 & 7) ^ (r0 & 7);
  const int r1 = P1 >> 3, kl1 = (P1 & 7) ^ (r1 & 7);

  for (int kc = 0; kc < FLAT_IN; kc += 64) {
    GLDS16(Ahi  + (size_t)(m0 + r0) * FLAT_IN + kc + kl0 * 8, &sm[0][P0 * 8]);
    GLDS16(Ahi  + (size_t)(m0 + r1) * FLAT_IN + kc + kl1 * 8, &sm[0][P1 * 8]);
    GLDS16(Amid + (size_t)(m0 + r0) * FLAT_IN + kc + kl0 * 8, &sm[1][P0 * 8]);
    GLDS16(Amid + (size_t)(m0 + r1) * FLAT_IN + kc + kl1 * 8, &sm[1][P1 * 8]);
    GLDS16(Bhi  + (size_t)(n0 + r0) * FLAT_IN + kc + kl0 * 8, &sm[2][P0 * 8]);
    GLDS16(Bhi  + (size_t)(n0 + r1) * FLAT_IN + kc + kl1 * 8, &sm[2][P1 * 8]);
    GLDS16(Bmid + (size_t)(n0 + r0) * FLAT_IN + kc + kl0 * 8, &sm[3][P0 * 8]);
    GLDS16(Bmid + (size_t)(n0 + r1) * FLAT_IN + kc + kl1 * 8, &sm[3][P1 * 8]);
    __syncthreads();

#pragma unroll
    for (int ks = 0; ks < 2; ++ks) {
      short8 bf[2][2];
#pragma unroll
      for (int j = 0; j < 2; ++j) {
        int rr = wn + j * 16 + col;
        int off = rr * 64 + (((ks * 4 + quad) ^ (rr & 7)) * 8);
        bf[j][0] = *(const short8*)&sm[2][off];
        bf[j][1] = *(const short8*)&sm[3][off];
      }
#pragma unroll
      for (int i = 0; i < 2; ++i) {
        int rr = wm + i * 16 + col;
        int off = rr * 64 + (((ks * 4 + quad) ^ (rr & 7)) * 8);
        short8 a0 = *(const short8*)&sm[0][off];
        short8 a1 = *(const short8*)&sm[1][off];
#pragma unroll
        for (int j = 0; j < 2; ++j) {
          acc[i][j] = __builtin_amdgcn_mfma_f32_16x16x32_bf16(a0, bf[j][0], acc[i][j], 0, 0, 0);
          acc[i][j] = __builtin_amdgcn_mfma_f32_16x16x32_bf16(a0, bf[j][1], acc[i][j], 0, 0, 0);
          acc[i][j] = __builtin_amdgcn_mfma_f32_16x16x32_bf16(a1, bf[j][0], acc[i][j], 0, 0, 0);
        }
      }
    }
    __syncthreads();
  }

#pragma unroll
  for (int i = 0; i < 2; ++i)
#pragma unroll
    for (int j = 0; j < 2; ++j)
#pragma unroll
      for (int r = 0; r < 4; ++r) {
        int row = m0 + wm + i * 16 + quad * 4 + r;
        int c   = n0 + wn + j * 16 + col;
        float v = acc[i][j][r];
        S   [(size_t)row * PROJ_DIM + c] = v;
        Sf16[(size_t)row * PROJ_DIM + c] = f2h(v);
      }
}

// ---------------------------------------------------------------------------
// sim_topk: R5-proven core (tile 128x256, BK=64, GLDS staging, 512 thr,
// 8 waves 2x4, wave tile 64x64). Grid SWAPPED to (64 hchunks, 16 rowblocks)
// for XCD-disjoint mem slices. NEW cheap epilogue: per (row, 16-lane group)
// top-1 only (4-step shfl argmax, no LDS phase) -> part2[row][hc][4] float2.
// finalize rescues via exact top-4 rescore of the 256 group-maxima per row.
// ---------------------------------------------------------------------------
__global__ __launch_bounds__(512, 4) void sim_topk(
    const unsigned short* __restrict__ Af16,   // [2048][256]
    const unsigned short* __restrict__ Bf16,   // [16384][256]
    float2* __restrict__ part2)                // [2048][64][4]
{
  __shared__ __align__(16) unsigned short smA[128 * 64];  // 16 KB
  __shared__ __align__(16) unsigned short smB[256 * 64];  // 32 KB
  const int tid = threadIdx.x;
  const int lane = tid & 63, w = tid >> 6;
  const int quad = lane >> 4, col = lane & 15;
  const int wm = (w >> 2) * 64, wn = (w & 3) * 64;
  const int hc = blockIdx.x;            // head chunk (fast-varying -> XCD)
  const int h0 = hc * 256;
  const int m0 = blockIdx.y * 128;

  floatx4 acc[4][4];
#pragma unroll
  for (int i = 0; i < 4; ++i)
#pragma unroll
    for (int j = 0; j < 4; ++j) {
      acc[i][j][0] = 0.f; acc[i][j][1] = 0.f;
      acc[i][j][2] = 0.f; acc[i][j][3] = 0.f;
    }

  const int PA0 = tid, PA1 = tid + 512;
  const int ra0 = PA0 >> 3, ka0 = (PA0 & 7) ^ (ra0 & 7);
  const int ra1 = PA1 >> 3, ka1 = (PA1 & 7) ^ (ra1 & 7);
  int rb[4], kb[4];
#pragma unroll
  for (int t = 0; t < 4; ++t) {
    int P = t * 512 + tid;
    rb[t] = P >> 3; kb[t] = (P & 7) ^ (rb[t] & 7);
  }

  for (int kc = 0; kc < PROJ_DIM; kc += 64) {
    GLDS16(Af16 + (size_t)(m0 + ra0) * PROJ_DIM + kc + ka0 * 8, &smA[PA0 * 8]);
    GLDS16(Af16 + (size_t)(m0 + ra1) * PROJ_DIM + kc + ka1 * 8, &smA[PA1 * 8]);
#pragma unroll
    for (int t = 0; t < 4; ++t) {
      GLDS16(Bf16 + (size_t)(h0 + rb[t]) * PROJ_DIM + kc + kb[t] * 8,
             &smB[(t * 512 + tid) * 8]);
    }
    __syncthreads();

#pragma unroll
    for (int ks = 0; ks < 2; ++ks) {
      half8 a[4], bfr[4];
#pragma unroll
      for (int i = 0; i < 4; ++i) {
        int rr = wm + i * 16 + col;
        int off = rr * 64 + (((ks * 4 + quad) ^ (rr & 7)) * 8);
        a[i] = *(const half8*)&smA[off];
      }
#pragma unroll
      for (int j = 0; j < 4; ++j) {
        int rr = wn + j * 16 + col;
        int off = rr * 64 + (((ks * 4 + quad) ^ (rr & 7)) * 8);
        bfr[j] = *(const half8*)&smB[off];
      }
#pragma unroll
      for (int i = 0; i < 4; ++i)
#pragma unroll
        for (int j = 0; j < 4; ++j)
          acc[i][j] = __builtin_amdgcn_mfma_f32_16x16x32_f16(a[i], bfr[j], acc[i][j], 0, 0, 0);
    }
    __syncthreads();
  }

  // ---- cheap epilogue: per (row) top-1 of this wave's 64 heads ----
#pragma unroll
  for (int i = 0; i < 4; ++i)
#pragma unroll
    for (int r = 0; r < 4; ++r) {
      float b1 = acc[i][0][r]; int h1 = h0 + wn + col;
#pragma unroll
      for (int j = 1; j < 4; ++j) {
        float v = acc[i][j][r]; int h = h0 + wn + j * 16 + col;
        if (v > b1) { b1 = v; h1 = h; }
      }
#pragma unroll
      for (int m = 1; m <= 8; m <<= 1) {
        float ob = __shfl_xor(b1, m); int oh = __shfl_xor(h1, m);
        if (ob > b1 || (ob == b1 && oh < h1)) { b1 = ob; h1 = oh; }
      }
      if (col == 0) {
        int row = m0 + wm + i * 16 + quad * 4 + r;
        part2[((size_t)row * 64 + hc) * 4 + (w & 3)] =
            make_float2(b1, __int_as_float(h1));
      }
    }
}

// ---------------------------------------------------------------------------
// finalize: 256 group-maxima/row -> global top-4 (4 rounds of wave-argmax +
// mask), exact fp32 rescore of all 4, pick winner, gather logits row.
// ---------------------------------------------------------------------------
__global__ __launch_bounds__(64) void finalize(
    const float2* __restrict__ part2, const float* __restrict__ S,
    const float* __restrict__ Mem, const float* __restrict__ logits,
    float* __restrict__ out)
{
  const int row  = blockIdx.x;
  const int lane = threadIdx.x;

  float v[4]; int c[4];
#pragma unroll
  for (int t = 0; t < 4; ++t) {
    float2 p = part2[(size_t)row * 256 + t * 64 + lane];
    v[t] = p.x; c[t] = __float_as_int(p.y);
  }

  int cand[4];
#pragma unroll
  for (int t = 0; t < 4; ++t) {
    float lv = v[0]; int lh = c[0];
#pragma unroll
    for (int q = 1; q < 4; ++q)
      if (v[q] > lv || (v[q] == lv && c[q] < lh)) { lv = v[q]; lh = c[q]; }
#pragma unroll
    for (int d = 32; d; d >>= 1) {
      float ov = __shfl_xor(lv, d); int oh = __shfl_xor(lh, d);
      if (ov > lv || (ov == lv && oh < lh)) { lv = ov; lh = oh; }
    }
    cand[t] = lh;
#pragma unroll
    for (int q = 0; q < 4; ++q)
      if (c[q] == lh) v[q] = -3.4e38f;
  }

  // exact fp32 rescore of the 4 candidates (lane owns 4 k's)
  float4 sv = ((const float4*)(S + (size_t)row * PROJ_DIM))[lane];
  float bestv = -3.4e38f; int besth = 0x7fffffff;
#pragma unroll
  for (int t = 0; t < 4; ++t) {
    float4 mv = ((const float4*)(Mem + (size_t)cand[t] * PROJ_DIM))[lane];
    float d = sv.x * mv.x + sv.y * mv.y + sv.z * mv.z + sv.w * mv.w;
#pragma unroll
    for (int s = 32; s; s >>= 1) d += __shfl_xor(d, s);
    if (d > bestv || (d == bestv && cand[t] < besth)) { bestv = d; besth = cand[t]; }
  }
  out[(size_t)row * ACT_DIM + lane] = logits[(size_t)besth * ACT_DIM + lane];
}

// ---------------------------------------------------------------------------
extern "C" void kernel_launch(void* const* d_in, const int* in_sizes, int n_in,
                              void* d_out, int out_size, void* d_ws, size_t ws_size,
                              hipStream_t stream) {
  const float* state  = (const float*)d_in[0]; // [2048, 512]
  const float* rp     = (const float*)d_in[1]; // [512, 256]
  const float* mem    = (const float*)d_in[2]; // [16384, 256]
  const float* logits = (const float*)d_in[3]; // [16384, 64]
  float* out = (float*)d_out;                  // [2048, 64]

  // workspace (24 MB):
  //   [0, 2)M     st_hi  [2048][512] bf16
  //   [2, 4)M     st_mid
  //   [4, 4.25)M  rpT_hi [256][512] bf16
  //   [4.25,4.5)M rpT_mid
  //   [8, 16)M    mem_f16 [16384][256] f16
  //   [16,18)M    s      [2048][256] fp32
  //   [18,19)M    s_f16  [2048][256] f16
  //   [20,24)M    part2  [2048][64][4] float2 (4 MB)
  char* ws = (char*)d_ws;
  unsigned short* st_hi   = (unsigned short*)(ws);
  unsigned short* st_mid  = (unsigned short*)(ws + (2u  << 20));
  unsigned short* rpT_hi  = (unsigned short*)(ws + (4u  << 20));
  unsigned short* rpT_mid = (unsigned short*)(ws + (4u  << 20) + (256u << 10));
  unsigned short* mem_f16 = (unsigned short*)(ws + (8u  << 20));
  float*          s       = (float*)(ws + (16u << 20));
  unsigned short* s_f16   = (unsigned short*)(ws + (18u << 20));
  float2*         part2   = (float2*)(ws + (20u << 20));

  prep<<<1056, 256, 0, stream>>>(state, rp, st_hi, st_mid, rpT_hi, rpT_mid);

  gemm_conv<<<2176, 256, 0, stream>>>(st_hi, st_mid, rpT_hi, rpT_mid, mem,
                                      s, s_f16, mem_f16);

  sim_topk<<<dim3(64, 16), 512, 0, stream>>>(s_f16, mem_f16, part2);

  finalize<<<BATCH, 64, 0, stream>>>(part2, s, mem, logits, out);
}